// Round 7
// baseline (251.647 us; speedup 1.0000x reference)
//
#include <hip/hip_runtime.h>
#include <math.h>

#define D_FEAT 64
#define NG 8          // edge groups (private counters, one per XCD)
#define NR 8          // dst ranges (XCD-local scatter writes)
#define MAXTILES 1024 // lookback-scan state slots (1024 tiles x 1024 = 1M nodes max)

// ---------------------------------------------------------------------------
// ws layout (bytes):
//   [0,4)                      ticket
//   [4,8)                      pad
//   [8, 8+8*MAXTILES)          lookback states (ull: flag<<62 | value)
//   main:     priv NG*n ints | offsets n+1 | sorted_src E
//   fallback: counts n (becomes cursor) | offsets n+1 | sorted_src E
// memset zeroes ticket+states+(priv|counts) in ONE async memset node.
// ---------------------------------------------------------------------------

// wave-shuffle block exclusive scan; requires blockDim.x == 1024
__device__ __forceinline__ int block_scan_excl_1024(int v, int* smem16) {
    int lane = threadIdx.x & 63;
    int wid  = threadIdx.x >> 6;
    int x = v;
    #pragma unroll
    for (int d = 1; d < 64; d <<= 1) {
        int t = __shfl_up(x, d, 64);
        if (lane >= d) x += t;
    }
    if (lane == 63) smem16[wid] = x;          // wave inclusive totals
    __syncthreads();
    if (wid == 0) {
        int s = (lane < 16) ? smem16[lane] : 0;
        #pragma unroll
        for (int d = 1; d < 16; d <<= 1) {
            int t = __shfl_up(s, d, 64);
            if (lane >= d) s += t;
        }
        if (lane < 16) smem16[lane] = s;      // inclusive scan of wave totals
    }
    __syncthreads();
    int base = (wid > 0) ? smem16[wid - 1] : 0;
    return base + x - v;                      // exclusive prefix
}

// =========================== count phase ===================================

// edge-group-partitioned count: group g (blockIdx&7 -> XCD g) streams its
// contiguous 1/8 of the edge list once, coalesced; atomics hit priv[g][*],
// which only XCD g touches -> L2-local.
__global__ void count_group_kernel(const int* __restrict__ dst,
                                   int* __restrict__ priv,
                                   int n_nodes, int n_edges, int egroup) {
    int g = blockIdx.x & (NG - 1);
    int c = blockIdx.x >> 3;
    int nchunks = gridDim.x >> 3;
    int ebeg = g * egroup;
    int eend = ebeg + egroup; if (eend > n_edges) eend = n_edges;
    int* cnt = priv + (size_t)g * n_nodes;
    int stride = nchunks * blockDim.x;
    for (int e = ebeg + c * blockDim.x + threadIdx.x; e < eend; e += stride) {
        atomicAdd(&cnt[dst[e]], 1);
    }
}

// fallback count: dst-range-partitioned histogram into a single counts array
__global__ void hist_part_kernel(const int* __restrict__ dst,
                                 int* __restrict__ counts,
                                 int n_edges, int nodes_per_range) {
    int r = blockIdx.x & (NR - 1);
    int c = blockIdx.x / NR;
    int nchunks = gridDim.x / NR;
    int lo = r * nodes_per_range;
    int hi = lo + nodes_per_range;
    int stride = nchunks * blockDim.x;
    for (int e = c * blockDim.x + threadIdx.x; e < n_edges; e += stride) {
        int d = dst[e];
        if (d >= lo && d < hi) atomicAdd(&counts[d], 1);
    }
}

// =========================== single-pass scan ==============================

// Decoupled-lookback exclusive scan over per-node degree totals.
// If priv != null: per-node cross-group exclusive prefix is computed and
// rewritten into priv in place (relative sub-segment starts), node total is
// the scanned value. Else: value = counts[i], and counts[i] is overwritten
// with the absolute exclusive prefix (cursor for the fallback scatter).
// Ticket-ordered blocks -> lookback only waits on already-running tickets.
__global__ void scan_lookback_kernel(int* __restrict__ priv,
                                     int* __restrict__ counts,
                                     int* __restrict__ offsets,
                                     unsigned long long* __restrict__ states,
                                     int* __restrict__ ticket,
                                     int n_nodes, int n_edges, int ntiles) {
    __shared__ int smem16[16];
    __shared__ int s_tile, s_prefix, s_btotal;
    int tid = threadIdx.x;
    if (tid == 0) s_tile = atomicAdd(ticket, 1);
    __syncthreads();
    int tile = s_tile;
    int i = tile * 1024 + tid;

    int total = 0;
    if (i < n_nodes) {
        if (priv != nullptr) {
            int run = 0;
            #pragma unroll
            for (int g = 0; g < NG; ++g) {
                size_t idx = (size_t)g * n_nodes + i;
                int t = priv[idx];
                priv[idx] = run;          // relative sub-segment start
                run += t;
            }
            total = run;
        } else {
            total = counts[i];
        }
    }
    int excl = block_scan_excl_1024(total, smem16);
    if (tid == 1023) s_btotal = excl + total;     // block sum
    __syncthreads();
    int btotal = s_btotal;

    if (tid == 0) {
        if (tile == 0) {
            atomicExch(&states[0], (2ULL << 62) | (unsigned long long)btotal);
            s_prefix = 0;
        } else {
            atomicExch(&states[tile], (1ULL << 62) | (unsigned long long)btotal);
            int pref = 0;
            int t = tile - 1;
            while (t >= 0) {
                unsigned long long st = atomicAdd(&states[t], 0ULL);
                unsigned long long f = st >> 62;
                if (f == 2ULL) { pref += (int)(st & 0x3FFFFFFFFFFFFFFFULL); break; }
                if (f == 1ULL) { pref += (int)(st & 0x3FFFFFFFFFFFFFFFULL); --t; }
                // f == 0: predecessor not published yet -> spin
            }
            atomicExch(&states[tile],
                       (2ULL << 62) | (unsigned long long)(pref + btotal));
            s_prefix = pref;
        }
    }
    __syncthreads();
    int bp = s_prefix;
    if (i < n_nodes) {
        int o = bp + excl;
        offsets[i] = o;
        if (priv == nullptr) counts[i] = o;       // cursor init (fallback)
    }
    if (tid == 0 && tile == ntiles - 1) offsets[n_nodes] = bp + btotal;
}

// =========================== scatter phase =================================

// block (r,g,c): r = blockIdx&7 -> XCD r. Streams group g's edge chunk, keeps
// dst in range r. Cursor atomics (priv[g] slice for range r) and sorted_src
// writes (range-r segment) are both XCD-r L2-local.
__global__ void scatter_rg_kernel(const int* __restrict__ src,
                                  const int* __restrict__ dst,
                                  const int* __restrict__ offsets,
                                  int* __restrict__ priv,
                                  int* __restrict__ sorted_src,
                                  int n_nodes, int n_edges, int egroup,
                                  int nodes_per_range) {
    int r = blockIdx.x & (NR - 1);
    int g = (blockIdx.x >> 3) & (NG - 1);
    int c = blockIdx.x >> 6;
    int nchunks = gridDim.x >> 6;
    int lo = r * nodes_per_range;
    int hi = lo + nodes_per_range;
    int ebeg = g * egroup;
    int eend = ebeg + egroup; if (eend > n_edges) eend = n_edges;
    int* cur = priv + (size_t)g * n_nodes;
    int stride = nchunks * blockDim.x;
    for (int e = ebeg + c * blockDim.x + threadIdx.x; e < eend; e += stride) {
        int d = dst[e];
        if (d >= lo && d < hi) {
            int pos = offsets[d] + atomicAdd(&cur[d], 1);
            sorted_src[pos] = src[e];
        }
    }
}

// fallback scatter: cursor = counts array holding absolute positions
__global__ void scatter_part_kernel(const int* __restrict__ src,
                                    const int* __restrict__ dst,
                                    int* __restrict__ cursor,
                                    int* __restrict__ sorted_src,
                                    int n_edges, int nodes_per_range) {
    int r = blockIdx.x & (NR - 1);
    int c = blockIdx.x / NR;
    int nchunks = gridDim.x / NR;
    int lo = r * nodes_per_range;
    int hi = lo + nodes_per_range;
    int stride = nchunks * blockDim.x;
    for (int e = c * blockDim.x + threadIdx.x; e < n_edges; e += stride) {
        int d = dst[e];
        if (d >= lo && d < hi) {
            int pos = atomicAdd(&cursor[d], 1);
            sorted_src[pos] = src[e];
        }
    }
}

// ============================== pull phase =================================

// one wave per node; 4 groups x 16 lanes, float4 gathers, 2-deep unroll.
__global__ void pull_max_kernel(const float* __restrict__ inp,
                                const int* __restrict__ offsets,
                                const int* __restrict__ sorted_src,
                                float* __restrict__ out, int n_nodes) {
    int gtid = blockIdx.x * blockDim.x + threadIdx.x;
    int node = gtid >> 6;
    if (node >= n_nodes) return;
    int lane = threadIdx.x & 63;
    int g = lane >> 4;
    int l = lane & 15;

    int beg = offsets[node];
    int end = offsets[node + 1];

    const float4* inp4 = reinterpret_cast<const float4*>(inp);
    float4 own = inp4[(size_t)node * 16 + l];

    float4 m;
    m.x = -INFINITY; m.y = -INFINITY; m.z = -INFINITY; m.w = -INFINITY;
    int j = beg + g;
    for (; j + 4 < end; j += 8) {
        int s0 = sorted_src[j];
        int s1 = sorted_src[j + 4];
        float4 v0 = inp4[(size_t)s0 * 16 + l];
        float4 v1 = inp4[(size_t)s1 * 16 + l];
        m.x = fmaxf(m.x, fmaxf(v0.x, v1.x));
        m.y = fmaxf(m.y, fmaxf(v0.y, v1.y));
        m.z = fmaxf(m.z, fmaxf(v0.z, v1.z));
        m.w = fmaxf(m.w, fmaxf(v0.w, v1.w));
    }
    if (j < end) {
        int s = sorted_src[j];
        float4 v = inp4[(size_t)s * 16 + l];
        m.x = fmaxf(m.x, v.x);
        m.y = fmaxf(m.y, v.y);
        m.z = fmaxf(m.z, v.z);
        m.w = fmaxf(m.w, v.w);
    }
    m.x = fmaxf(m.x, __shfl_xor(m.x, 16, 64));
    m.y = fmaxf(m.y, __shfl_xor(m.y, 16, 64));
    m.z = fmaxf(m.z, __shfl_xor(m.z, 16, 64));
    m.w = fmaxf(m.w, __shfl_xor(m.w, 16, 64));
    m.x = fmaxf(m.x, __shfl_xor(m.x, 32, 64));
    m.y = fmaxf(m.y, __shfl_xor(m.y, 32, 64));
    m.z = fmaxf(m.z, __shfl_xor(m.z, 32, 64));
    m.w = fmaxf(m.w, __shfl_xor(m.w, 32, 64));

    if (beg == end) m = own;   // isolated node keeps own feature

    float4* out4 = reinterpret_cast<float4*>(out);
    if (lane < 16) {
        out4[(size_t)node * 32 + l] = own;
    } else if (lane < 32) {
        out4[(size_t)node * 32 + 16 + l] = m;
    }
}

// ===========================================================================

extern "C" void kernel_launch(void* const* d_in, const int* in_sizes, int n_in,
                              void* d_out, int out_size, void* d_ws, size_t ws_size,
                              hipStream_t stream) {
    const float* inp = (const float*)d_in[0];
    const int* src = (const int*)d_in[1];
    const int* dst = (const int*)d_in[2];
    float* out = (float*)d_out;

    int n_nodes = in_sizes[0] / D_FEAT;
    int n_edges = in_sizes[1];

    int ntiles = (n_nodes + 1023) / 1024;          // <= MAXTILES for n <= 1M
    int nodes_per_range = (n_nodes + NR - 1) / NR;
    int egroup = (n_edges + NG - 1) / NG;

    char* base = (char*)d_ws;
    int* ticket = (int*)base;
    unsigned long long* states = (unsigned long long*)(base + 8);
    int* after = (int*)(base + 8 + 8 * MAXTILES);
    size_t head_bytes = 8 + 8 * (size_t)MAXTILES;

    size_t need_main = head_bytes +
        ((size_t)NG * n_nodes + (size_t)(n_nodes + 1) + (size_t)n_edges) * sizeof(int);

    if (ws_size >= need_main) {
        // ------------------- main path -------------------
        int* priv = after;                                     // NG*n
        int* offsets = priv + (size_t)NG * n_nodes;            // n+1
        int* sorted_src = offsets + n_nodes + 1;               // E

        size_t zero_bytes = head_bytes + (size_t)NG * n_nodes * sizeof(int);
        hipMemsetAsync(d_ws, 0, zero_bytes, stream);

        count_group_kernel<<<NG * 256, 256, 0, stream>>>(dst, priv, n_nodes,
                                                         n_edges, egroup);
        scan_lookback_kernel<<<ntiles, 1024, 0, stream>>>(priv, nullptr, offsets,
                                                          states, ticket,
                                                          n_nodes, n_edges, ntiles);
        scatter_rg_kernel<<<NR * NG * 32, 256, 0, stream>>>(src, dst, offsets,
                                                            priv, sorted_src,
                                                            n_nodes, n_edges,
                                                            egroup, nodes_per_range);
        {
            int total = n_nodes * 64;
            pull_max_kernel<<<(total + 255) / 256, 256, 0, stream>>>(
                inp, offsets, sorted_src, out, n_nodes);
        }
    } else {
        // ------------------- fallback path -------------------
        int* counts = after;                                   // n (becomes cursor)
        int* offsets = counts + n_nodes;                       // n+1
        int* sorted_src = offsets + n_nodes + 1;               // E

        size_t zero_bytes = head_bytes + (size_t)n_nodes * sizeof(int);
        hipMemsetAsync(d_ws, 0, zero_bytes, stream);

        hist_part_kernel<<<NR * 256, 256, 0, stream>>>(dst, counts, n_edges,
                                                       nodes_per_range);
        scan_lookback_kernel<<<ntiles, 1024, 0, stream>>>(nullptr, counts, offsets,
                                                          states, ticket,
                                                          n_nodes, n_edges, ntiles);
        scatter_part_kernel<<<NR * 256, 256, 0, stream>>>(src, dst, counts,
                                                          sorted_src, n_edges,
                                                          nodes_per_range);
        {
            int total = n_nodes * 64;
            pull_max_kernel<<<(total + 255) / 256, 256, 0, stream>>>(
                inp, offsets, sorted_src, out, n_nodes);
        }
    }
}

// Round 8
// 245.643 us; speedup vs baseline: 1.0244x; 1.0244x over previous
//
#include <hip/hip_runtime.h>
#include <math.h>

#define D_FEAT 64
#define SCAN_BLOCK 1024
#define NG 8          // edge groups (private counters, one per XCD)
#define NR 8          // dst ranges (XCD-local scatter writes)

// ---------------------------------------------------------------------------
// main ws layout (ints):
//   priv       : NG * n_nodes   (zeroed by ONE hipMemsetAsync; counts ->
//                                cross-group relative prefixes -> cursors)
//   offsets    : n_nodes + 1
//   blocksums  : nScanBlocks
//   sorted_src : n_edges
// fallback layout: counts n (memset; becomes cursor) | offsets | blocksums | E
// ---------------------------------------------------------------------------

// wave-shuffle block exclusive scan; requires blockDim.x == 1024
__device__ __forceinline__ int block_scan_excl_1024(int v, int* smem16) {
    int lane = threadIdx.x & 63;
    int wid  = threadIdx.x >> 6;
    int x = v;
    #pragma unroll
    for (int d = 1; d < 64; d <<= 1) {
        int t = __shfl_up(x, d, 64);
        if (lane >= d) x += t;
    }
    if (lane == 63) smem16[wid] = x;          // wave inclusive totals
    __syncthreads();
    if (wid == 0) {
        int s = (lane < 16) ? smem16[lane] : 0;
        #pragma unroll
        for (int d = 1; d < 16; d <<= 1) {
            int t = __shfl_up(s, d, 64);
            if (lane >= d) s += t;
        }
        if (lane < 16) smem16[lane] = s;      // inclusive scan of wave totals
    }
    __syncthreads();
    int base = (wid > 0) ? smem16[wid - 1] : 0;
    return base + x - v;                      // exclusive prefix
}

// =========================== count phase ===================================

// edge-group-partitioned count: group g (blockIdx&7 -> XCD g) streams its
// contiguous 1/8 of the edge list once, coalesced; atomics hit priv[g][*],
// which only XCD g touches -> L2-local.
__global__ void count_group_kernel(const int* __restrict__ dst,
                                   int* __restrict__ priv,
                                   int n_nodes, int n_edges, int egroup) {
    int g = blockIdx.x & (NG - 1);
    int c = blockIdx.x >> 3;
    int nchunks = gridDim.x >> 3;
    int ebeg = g * egroup;
    int eend = ebeg + egroup; if (eend > n_edges) eend = n_edges;
    int* cnt = priv + (size_t)g * n_nodes;
    int stride = nchunks * blockDim.x;
    for (int e = ebeg + c * blockDim.x + threadIdx.x; e < eend; e += stride) {
        atomicAdd(&cnt[dst[e]], 1);
    }
}

// fallback count: dst-range-partitioned histogram into a single counts array
__global__ void hist_part_kernel(const int* __restrict__ dst,
                                 int* __restrict__ counts,
                                 int n_edges, int nodes_per_range) {
    int r = blockIdx.x & (NR - 1);
    int c = blockIdx.x / NR;
    int nchunks = gridDim.x / NR;
    int lo = r * nodes_per_range;
    int hi = lo + nodes_per_range;
    int stride = nchunks * blockDim.x;
    for (int e = c * blockDim.x + threadIdx.x; e < n_edges; e += stride) {
        int d = dst[e];
        if (d >= lo && d < hi) atomicAdd(&counts[d], 1);
    }
}

// =========================== scan phase ====================================

// fused: per-node cross-group exclusive prefix (rewrites priv in place),
// node totals block-scanned into offsets + blocksums.
__global__ void scanA_fused_kernel(int* __restrict__ priv,
                                   int* __restrict__ offsets,
                                   int* __restrict__ blocksums, int n_nodes) {
    __shared__ int smem16[16];
    int i = blockIdx.x * SCAN_BLOCK + threadIdx.x;
    int total = 0;
    if (i < n_nodes) {
        int run = 0;
        #pragma unroll
        for (int g = 0; g < NG; ++g) {
            size_t idx = (size_t)g * n_nodes + i;
            int t = priv[idx];
            priv[idx] = run;      // becomes sub-segment start (relative)
            run += t;
        }
        total = run;
    }
    int excl = block_scan_excl_1024(total, smem16);
    if (i < n_nodes) offsets[i] = excl;
    if (threadIdx.x == SCAN_BLOCK - 1) blocksums[blockIdx.x] = excl + total;
}

__global__ void scanA_plain_kernel(const int* __restrict__ counts,
                                   int* __restrict__ offsets,
                                   int* __restrict__ blocksums, int n) {
    __shared__ int smem16[16];
    int i = blockIdx.x * SCAN_BLOCK + threadIdx.x;
    int v = (i < n) ? counts[i] : 0;
    int e = block_scan_excl_1024(v, smem16);
    if (i < n) offsets[i] = e;
    if (threadIdx.x == SCAN_BLOCK - 1) blocksums[blockIdx.x] = e + v;
}

__global__ void scanB_kernel(int* __restrict__ blocksums, int nb) {
    __shared__ int smem16[16];
    int v = ((int)threadIdx.x < nb) ? blocksums[threadIdx.x] : 0;
    int e = block_scan_excl_1024(v, smem16);
    if ((int)threadIdx.x < nb) blocksums[threadIdx.x] = e;
}

__global__ void scanC_kernel(int* __restrict__ offsets,
                             const int* __restrict__ blocksums,
                             int n, int n_edges) {
    int i = blockIdx.x * SCAN_BLOCK + threadIdx.x;
    if (i < n) offsets[i] += blocksums[blockIdx.x];
    if (i == 0) offsets[n] = n_edges;
}

__global__ void scanC_plain_kernel(int* __restrict__ offsets,
                                   int* __restrict__ cursor,
                                   const int* __restrict__ blocksums,
                                   int n, int n_edges) {
    int i = blockIdx.x * SCAN_BLOCK + threadIdx.x;
    if (i < n) {
        int o = offsets[i] + blocksums[blockIdx.x];
        offsets[i] = o;
        cursor[i] = o;
    }
    if (i == 0) offsets[n] = n_edges;
}

// =========================== scatter phase =================================

// block (r,g,c): r = blockIdx&7 -> XCD r. Streams group g's edge chunk, keeps
// dst in range r. Cursor atomics (priv[g] slice for range r) and sorted_src
// writes (range-r segment) are both XCD-r L2-local.
__global__ void scatter_rg_kernel(const int* __restrict__ src,
                                  const int* __restrict__ dst,
                                  const int* __restrict__ offsets,
                                  int* __restrict__ priv,
                                  int* __restrict__ sorted_src,
                                  int n_nodes, int n_edges, int egroup,
                                  int nodes_per_range) {
    int r = blockIdx.x & (NR - 1);
    int g = (blockIdx.x >> 3) & (NG - 1);
    int c = blockIdx.x >> 6;
    int nchunks = gridDim.x >> 6;
    int lo = r * nodes_per_range;
    int hi = lo + nodes_per_range;
    int ebeg = g * egroup;
    int eend = ebeg + egroup; if (eend > n_edges) eend = n_edges;
    int* cur = priv + (size_t)g * n_nodes;
    int stride = nchunks * blockDim.x;
    for (int e = ebeg + c * blockDim.x + threadIdx.x; e < eend; e += stride) {
        int d = dst[e];
        if (d >= lo && d < hi) {
            int pos = offsets[d] + atomicAdd(&cur[d], 1);
            sorted_src[pos] = src[e];
        }
    }
}

__global__ void scatter_part_kernel(const int* __restrict__ src,
                                    const int* __restrict__ dst,
                                    int* __restrict__ cursor,
                                    int* __restrict__ sorted_src,
                                    int n_edges, int nodes_per_range) {
    int r = blockIdx.x & (NR - 1);
    int c = blockIdx.x / NR;
    int nchunks = gridDim.x / NR;
    int lo = r * nodes_per_range;
    int hi = lo + nodes_per_range;
    int stride = nchunks * blockDim.x;
    for (int e = c * blockDim.x + threadIdx.x; e < n_edges; e += stride) {
        int d = dst[e];
        if (d >= lo && d < hi) {
            int pos = atomicAdd(&cursor[d], 1);
            sorted_src[pos] = src[e];
        }
    }
}

// ============================== pull phase =================================

// one wave per node; 4 groups x 16 lanes, float4 gathers, 2-deep unroll.
__global__ void pull_max_kernel(const float* __restrict__ inp,
                                const int* __restrict__ offsets,
                                const int* __restrict__ sorted_src,
                                float* __restrict__ out, int n_nodes) {
    int gtid = blockIdx.x * blockDim.x + threadIdx.x;
    int node = gtid >> 6;
    if (node >= n_nodes) return;
    int lane = threadIdx.x & 63;
    int g = lane >> 4;
    int l = lane & 15;

    int beg = offsets[node];
    int end = offsets[node + 1];

    const float4* inp4 = reinterpret_cast<const float4*>(inp);
    float4 own = inp4[(size_t)node * 16 + l];

    float4 m;
    m.x = -INFINITY; m.y = -INFINITY; m.z = -INFINITY; m.w = -INFINITY;
    int j = beg + g;
    for (; j + 4 < end; j += 8) {
        int s0 = sorted_src[j];
        int s1 = sorted_src[j + 4];
        float4 v0 = inp4[(size_t)s0 * 16 + l];
        float4 v1 = inp4[(size_t)s1 * 16 + l];
        m.x = fmaxf(m.x, fmaxf(v0.x, v1.x));
        m.y = fmaxf(m.y, fmaxf(v0.y, v1.y));
        m.z = fmaxf(m.z, fmaxf(v0.z, v1.z));
        m.w = fmaxf(m.w, fmaxf(v0.w, v1.w));
    }
    if (j < end) {
        int s = sorted_src[j];
        float4 v = inp4[(size_t)s * 16 + l];
        m.x = fmaxf(m.x, v.x);
        m.y = fmaxf(m.y, v.y);
        m.z = fmaxf(m.z, v.z);
        m.w = fmaxf(m.w, v.w);
    }
    m.x = fmaxf(m.x, __shfl_xor(m.x, 16, 64));
    m.y = fmaxf(m.y, __shfl_xor(m.y, 16, 64));
    m.z = fmaxf(m.z, __shfl_xor(m.z, 16, 64));
    m.w = fmaxf(m.w, __shfl_xor(m.w, 16, 64));
    m.x = fmaxf(m.x, __shfl_xor(m.x, 32, 64));
    m.y = fmaxf(m.y, __shfl_xor(m.y, 32, 64));
    m.z = fmaxf(m.z, __shfl_xor(m.z, 32, 64));
    m.w = fmaxf(m.w, __shfl_xor(m.w, 32, 64));

    if (beg == end) m = own;   // isolated node keeps own feature

    float4* out4 = reinterpret_cast<float4*>(out);
    if (lane < 16) {
        out4[(size_t)node * 32 + l] = own;
    } else if (lane < 32) {
        out4[(size_t)node * 32 + 16 + l] = m;
    }
}

// ===========================================================================

extern "C" void kernel_launch(void* const* d_in, const int* in_sizes, int n_in,
                              void* d_out, int out_size, void* d_ws, size_t ws_size,
                              hipStream_t stream) {
    const float* inp = (const float*)d_in[0];
    const int* src = (const int*)d_in[1];
    const int* dst = (const int*)d_in[2];
    float* out = (float*)d_out;

    int n_nodes = in_sizes[0] / D_FEAT;
    int n_edges = in_sizes[1];

    int nScanBlocks = (n_nodes + SCAN_BLOCK - 1) / SCAN_BLOCK;
    int nodes_per_range = (n_nodes + NR - 1) / NR;
    int egroup = (n_edges + NG - 1) / NG;

    int* ws = (int*)d_ws;
    size_t need_main = ((size_t)NG * n_nodes + (size_t)(n_nodes + 1) +
                        (size_t)nScanBlocks + (size_t)n_edges) * sizeof(int);

    if (ws_size >= need_main) {
        // ------------------- main path -------------------
        int* priv = ws;                                        // NG*n
        int* offsets = ws + (size_t)NG * n_nodes;              // n+1
        int* blocksums = offsets + n_nodes + 1;                // nScanBlocks
        int* sorted_src = blocksums + nScanBlocks;             // E

        hipMemsetAsync(priv, 0, (size_t)NG * n_nodes * sizeof(int), stream);
        count_group_kernel<<<NG * 256, 256, 0, stream>>>(dst, priv, n_nodes,
                                                         n_edges, egroup);
        scanA_fused_kernel<<<nScanBlocks, SCAN_BLOCK, 0, stream>>>(priv, offsets,
                                                                   blocksums, n_nodes);
        scanB_kernel<<<1, SCAN_BLOCK, 0, stream>>>(blocksums, nScanBlocks);
        scanC_kernel<<<nScanBlocks, SCAN_BLOCK, 0, stream>>>(offsets, blocksums,
                                                             n_nodes, n_edges);
        scatter_rg_kernel<<<NR * NG * 32, 256, 0, stream>>>(src, dst, offsets,
                                                            priv, sorted_src,
                                                            n_nodes, n_edges,
                                                            egroup, nodes_per_range);
        {
            int total = n_nodes * 64;
            pull_max_kernel<<<(total + 255) / 256, 256, 0, stream>>>(
                inp, offsets, sorted_src, out, n_nodes);
        }
    } else {
        // ------------------- fallback path -------------------
        int* counts = ws;                                      // n (becomes cursor)
        int* offsets = ws + n_nodes;                           // n+1
        int* blocksums = offsets + n_nodes + 1;                // nScanBlocks
        int* sorted_src = blocksums + nScanBlocks;             // E

        hipMemsetAsync(counts, 0, (size_t)n_nodes * sizeof(int), stream);
        hist_part_kernel<<<NR * 256, 256, 0, stream>>>(dst, counts, n_edges,
                                                       nodes_per_range);
        scanA_plain_kernel<<<nScanBlocks, SCAN_BLOCK, 0, stream>>>(counts, offsets,
                                                                   blocksums, n_nodes);
        scanB_kernel<<<1, SCAN_BLOCK, 0, stream>>>(blocksums, nScanBlocks);
        scanC_plain_kernel<<<nScanBlocks, SCAN_BLOCK, 0, stream>>>(offsets, counts,
                                                                   blocksums,
                                                                   n_nodes, n_edges);
        scatter_part_kernel<<<NR * 256, 256, 0, stream>>>(src, dst, counts,
                                                          sorted_src, n_edges,
                                                          nodes_per_range);
        {
            int total = n_nodes * 64;
            pull_max_kernel<<<(total + 255) / 256, 256, 0, stream>>>(
                inp, offsets, sorted_src, out, n_nodes);
        }
    }
}